// Round 12
// baseline (168.199 us; speedup 1.0000x reference)
//
#include <hip/hip_runtime.h>
#include <cstdint>

#define N_TOK 4096
#define DMODEL 512
#define NHEADS 8
#define HDIM 64

typedef unsigned short u16;
typedef __bf16 bf16x8 __attribute__((ext_vector_type(8)));
typedef float f32x4 __attribute__((ext_vector_type(4)));

union U128 { uint4 u; bf16x8 b; u16 s[8]; };

__device__ __forceinline__ u16 f2bf(float f) {           // RNE
  uint32_t u = __builtin_bit_cast(uint32_t, f);
  u += 0x7FFFu + ((u >> 16) & 1u);
  return (u16)(u >> 16);
}
__device__ __forceinline__ float bf2f(u16 s) {
  uint32_t u = ((uint32_t)s) << 16;
  return __builtin_bit_cast(float, u);
}

#if __has_builtin(__builtin_amdgcn_exp2f)
#define EXP2(x) __builtin_amdgcn_exp2f(x)
#else
#define EXP2(x) __expf((x) * 0.6931471805599453f)
#endif

// v_cvt_pk_bf16_f32: packs two f32 into one u32 of 2 bf16 (RNE), src0 -> lo.
__device__ __forceinline__ uint32_t cvtpk(float lo, float hi) {
  uint32_t r;
  asm("v_cvt_pk_bf16_f32 %0, %1, %2" : "=v"(r) : "v"(lo), "v"(hi));
  return r;
}

// async global->LDS, 16B/lane, dest = wave-uniform base + lane*16
__device__ __forceinline__ void ldg2lds16(const void* g, void* s) {
  __builtin_amdgcn_global_load_lds(
      (const __attribute__((address_space(1))) void*)g,
      (__attribute__((address_space(3))) void*)s, 16, 0, 0);
}

// ---------------------------------------------------------------------------
// Kernel 0: fp32 -> bf16 pre-convert of Q,K,V,WQ,WK,WV,WO.  7168 x 256.
// (r19 lesson: conversion lives in coalesced streaming passes; staging bf16.)
// ---------------------------------------------------------------------------
__global__ __launch_bounds__(256) void cvt7_kernel(
    const float* __restrict__ Q, const float* __restrict__ K, const float* __restrict__ V,
    const float* __restrict__ WQ, const float* __restrict__ WK, const float* __restrict__ WV,
    const float* __restrict__ WO,
    u16* __restrict__ Qb, u16* __restrict__ Kb, u16* __restrict__ Vb,
    u16* __restrict__ WQb, u16* __restrict__ WKb, u16* __restrict__ WVb,
    u16* __restrict__ WOb)
{
  int b = blockIdx.x;
  const float* src; u16* dst; int rel;
  if      (b < 2048) { src = Q;  dst = Qb;  rel = b; }
  else if (b < 4096) { src = K;  dst = Kb;  rel = b - 2048; }
  else if (b < 6144) { src = V;  dst = Vb;  rel = b - 4096; }
  else if (b < 6400) { src = WQ; dst = WQb; rel = b - 6144; }
  else if (b < 6656) { src = WK; dst = WKb; rel = b - 6400; }
  else if (b < 6912) { src = WV; dst = WVb; rel = b - 6656; }
  else               { src = WO; dst = WOb; rel = b - 6912; }
  int i = (rel * 256 + threadIdx.x) * 4;
  float4 f = *(const float4*)(src + i);
  ushort4 o;
  o.x = f2bf(f.x); o.y = f2bf(f.y); o.z = f2bf(f.z); o.w = f2bf(f.w);
  *(ushort4*)(dst + i) = o;
}

// ---------------------------------------------------------------------------
// Kernel 1 (r20, verified): fused QKV projection with COALESCED staging
// (8 consecutive rows x 128B per global_load_lds, rule-21c swizzle).
// 128x64 tile, m=2, double-buffered.  grid (32, 8, 3), block 256.
// ---------------------------------------------------------------------------
__global__ __launch_bounds__(256) void proj3_kernel(
    const u16* __restrict__ Qb, const u16* __restrict__ Kb, const u16* __restrict__ Vb,
    const u16* __restrict__ WQb, const u16* __restrict__ WKb, const u16* __restrict__ WVb,
    const float* __restrict__ bQ, const float* __restrict__ bK, const float* __restrict__ bV,
    u16* __restrict__ Qs, u16* __restrict__ Ks, u16* __restrict__ Vt)
{
  const int z = blockIdx.z;
  const u16* A      = (z == 0) ? Qb : (z == 1) ? Kb : Vb;
  const u16* W      = (z == 0) ? WQb : (z == 1) ? WKb : WVb;
  const float* bias = (z == 0) ? bQ : (z == 1) ? bK : bV;

  const int m0 = blockIdx.x * 128;
  const int j0 = blockIdx.y * 64;
  const int tid = threadIdx.x;
  const int w = tid >> 6, lane = tid & 63, quad = lane >> 4, l = lane & 15;

  __shared__ bf16x8 sA[2][128 * 8];  // [row][slot] 32 KB
  __shared__ bf16x8 sB[2][64 * 8];   // [row][slot] 16 KB

  const f32x4 zero = {0.f, 0.f, 0.f, 0.f};
  f32x4 acc[2][4];
#pragma unroll
  for (int m = 0; m < 2; ++m)
#pragma unroll
    for (int s = 0; s < 4; ++s) acc[m][s] = zero;

  const int rsub = lane >> 3;            // 0..7: row within 8-row group
  const int gchunk = (lane & 7) ^ rsub;  // pre-swizzled source k-chunk

  auto stage = [&](int kt, int buf) {
    const int k0 = kt * 64;
#pragma unroll
    for (int t = 0; t < 4; ++t) {
      const int row = w * 32 + t * 8;
      const u16* ag = A + (size_t)(m0 + row + rsub) * DMODEL + k0 + gchunk * 8;
      ldg2lds16(ag, (char*)&sA[buf][row * 8]);
    }
#pragma unroll
    for (int i = 0; i < 2; ++i) {
      const int row = w * 16 + i * 8;
      const u16* bg = W + (size_t)(j0 + row + rsub) * DMODEL + k0 + gchunk * 8;
      ldg2lds16(bg, (char*)&sB[buf][row * 8]);
    }
  };

  stage(0, 0);
  __syncthreads();
  for (int kt = 0; kt < 8; ++kt) {
    const int buf = kt & 1;
    if (kt + 1 < 8) stage(kt + 1, buf ^ 1);
#pragma unroll
    for (int c = 0; c < 2; ++c) {
      const int sl = (c * 4 + quad) ^ (l & 7);   // swizzled read slot
      bf16x8 af0 = sA[buf][(w * 32 + l) * 8 + sl];
      bf16x8 af1 = sA[buf][(w * 32 + 16 + l) * 8 + sl];
#pragma unroll
      for (int s = 0; s < 4; ++s) {
        bf16x8 bfb = sB[buf][(s * 16 + l) * 8 + sl];
        acc[0][s] = __builtin_amdgcn_mfma_f32_16x16x32_bf16(af0, bfb, acc[0][s], 0, 0, 0);
        acc[1][s] = __builtin_amdgcn_mfma_f32_16x16x32_bf16(af1, bfb, acc[1][s], 0, 0, 0);
      }
    }
    __syncthreads();
  }

#pragma unroll
  for (int m = 0; m < 2; ++m)
#pragma unroll
    for (int s = 0; s < 4; ++s) {
      int j = j0 + s * 16 + l;
      float bv = bias[j];
      int n0 = m0 + w * 32 + m * 16 + quad * 4;
      if (z < 2) {
        u16* Y = (z == 0) ? Qs : Ks;
#pragma unroll
        for (int r = 0; r < 4; ++r)
          Y[(size_t)(n0 + r) * DMODEL + j] = f2bf(acc[m][s][r] + bv);
      } else {
        ushort4 pk;
        pk.x = f2bf(acc[m][s][0] + bv); pk.y = f2bf(acc[m][s][1] + bv);
        pk.z = f2bf(acc[m][s][2] + bv); pk.w = f2bf(acc[m][s][3] + bv);
        *(ushort4*)(Vt + (size_t)j * N_TOK + n0) = pk;   // V^T write
      }
    }
}

// ---------------------------------------------------------------------------
// Kernel 2: flash attention — r16/r20 VERIFIED version RESTORED (absmax
// 0.03125, 43.9us).  r21's coalesced K/V staging is REVERTED: it bought
// zero attn time (L2-resident loads, not TA-bound) and changed absmax
// 0.031->0.066 unexplained — same silent-permutation risk as r15/r17.
// r8 geometry + r14 VALU diet + pbuf XOR-swizzle.  FROZEN.
// ---------------------------------------------------------------------------
__global__ __launch_bounds__(512, 4) void attn_kernel(
    const u16* __restrict__ Qs, const u16* __restrict__ Ks,
    const u16* __restrict__ Vt, u16* __restrict__ Opart, float* __restrict__ Lpart)
{
  const int hs = blockIdx.x;                 // h + 8*split
  const int h = hs & 7, split = hs >> 3;
  const int qt = blockIdx.y;
  const int tid = threadIdx.x;
  const int w = tid >> 6, lane = tid & 63, quad = lane >> 4, l = lane & 15;

  __shared__ bf16x8 kch[2][8][64];                 // 16 KB  [buf][d-chunk][key]
  __shared__ bf16x8 vch[2][8][64];                 // 16 KB  [buf][key-chunk][vd]
  __shared__ __align__(128) u16 pbuf[8][32][64];   // 32 KB  [wave][q][128B swizzled row]

  const int wq0 = qt * 256 + w * 32;

  // Q fragments (B-operand), pre-scaled by log2(e)/8
  bf16x8 qf[2][2];
#pragma unroll
  for (int c = 0; c < 2; ++c)
#pragma unroll
    for (int m = 0; m < 2; ++m) {
      U128 u;
      u.u = *(const uint4*)(Qs + (size_t)(wq0 + m * 16 + l) * DMODEL + h * HDIM + c * 32 + quad * 8);
#pragma unroll
      for (int j = 0; j < 8; ++j) u.s[j] = f2bf(bf2f(u.s[j]) * 0.18033688f);
      qf[c][m] = u.b;
    }

  // all-ones B-fragment for the lsum MFMA (bf16 1.0 = 0x3F80)
  U128 onesu;
#pragma unroll
  for (int j = 0; j < 8; ++j) onesu.s[j] = 0x3F80;

  const f32x4 zero = {0.f, 0.f, 0.f, 0.f};
  f32x4 o[2][4];
  f32x4 ol[2];               // lsum accumulators: ol[m][r] = lsum[q=m*16+quad*4+r]
  ol[0] = zero; ol[1] = zero;
#pragma unroll
  for (int m = 0; m < 2; ++m)
#pragma unroll
    for (int s = 0; s < 4; ++s) o[m][s] = zero;

  auto stage = [&](int it, int buf) {
    const int j0 = split * 1024 + it * 64;
    if (w < 4) {            // waves 0-3 stage K (8 KB)
      const u16* kg = Ks + (size_t)(j0 + lane) * DMODEL + h * HDIM + w * 16;
      ldg2lds16(kg,     (char*)&kch[buf][2 * w][0]);
      ldg2lds16(kg + 8, (char*)&kch[buf][2 * w + 1][0]);
    } else {                // waves 4-7 stage V^T (8 KB)
      const int w2 = w - 4;
      const u16* vg = Vt + (size_t)(h * HDIM + lane) * N_TOK + j0 + w2 * 16;
      ldg2lds16(vg,     (char*)&vch[buf][2 * w2][0]);
      ldg2lds16(vg + 8, (char*)&vch[buf][2 * w2 + 1][0]);
    }
  };

  stage(0, 0);
  __syncthreads();

  const unsigned swz = (unsigned)((l & 7) << 4);   // pbuf per-row XOR (row&7 == l&7)

  for (int it = 0; it < 16; ++it) {
    const int buf = it & 1;
    if (it + 1 < 16) stage(it + 1, buf ^ 1);   // prefetch overlaps compute

#pragma unroll
    for (int kh = 0; kh < 2; ++kh) {           // two 32-key halves
#pragma unroll
      for (int tt = 0; tt < 2; ++tt) {
        const int t = kh * 2 + tt;
        f32x4 sacc[2];
        sacc[0] = zero; sacc[1] = zero;
#pragma unroll
        for (int c = 0; c < 2; ++c) {
          bf16x8 kf = kch[buf][c * 4 + quad][t * 16 + l];
          sacc[0] = __builtin_amdgcn_mfma_f32_16x16x32_bf16(kf, qf[c][0], sacc[0], 0, 0, 0);
          sacc[1] = __builtin_amdgcn_mfma_f32_16x16x32_bf16(kf, qf[c][1], sacc[1], 0, 0, 0);
        }
#pragma unroll
        for (int m = 0; m < 2; ++m) {
          uint2 st;
          st.x = cvtpk(EXP2(sacc[m][0]), EXP2(sacc[m][1]));
          st.y = cvtpk(EXP2(sacc[m][2]), EXP2(sacc[m][3]));
          char* pb = (char*)&pbuf[w][m * 16 + l][0];
          *(uint2*)(pb + (((unsigned)(tt * 32 + quad * 8)) ^ swz)) = st;
        }
      }
      // PV for this key half (contraction = 32 keys, quad covers them)
      U128 pf0, pf1;
      const unsigned ro = ((unsigned)(quad * 16)) ^ swz;
      pf0.u = *(const uint4*)((const char*)&pbuf[w][l][0] + ro);
      pf1.u = *(const uint4*)((const char*)&pbuf[w][16 + l][0] + ro);
#pragma unroll
      for (int s = 0; s < 4; ++s) {
        bf16x8 vf = vch[buf][kh * 4 + quad][s * 16 + l];
        o[0][s] = __builtin_amdgcn_mfma_f32_16x16x32_bf16(pf0.b, vf, o[0][s], 0, 0, 0);
        o[1][s] = __builtin_amdgcn_mfma_f32_16x16x32_bf16(pf1.b, vf, o[1][s], 0, 0, 0);
      }
      // lsum = P . 1 on the matrix pipe
      ol[0] = __builtin_amdgcn_mfma_f32_16x16x32_bf16(pf0.b, onesu.b, ol[0], 0, 0, 0);
      ol[1] = __builtin_amdgcn_mfma_f32_16x16x32_bf16(pf1.b, onesu.b, ol[1], 0, 0, 0);
    }
    __syncthreads();   // publishes next buf's loads; orders buf reuse
  }

  // ol[m][r] holds lsum for q = m*16+quad*4+r, replicated across l=0..15.
  if (l == 0) {
    float* Lp = Lpart + ((size_t)split * NHEADS + h) * N_TOK + wq0;
#pragma unroll
    for (int m = 0; m < 2; ++m)
#pragma unroll
      for (int r = 0; r < 4; ++r)
        Lp[m * 16 + quad * 4 + r] = ol[m][r];
  }
  // Opart[split][h][q][vd] bf16 (unnormalized)
  u16* Ob = Opart + ((size_t)(split * NHEADS + h) * N_TOK + wq0) * 64;
#pragma unroll
  for (int m = 0; m < 2; ++m)
#pragma unroll
    for (int s = 0; s < 4; ++s)
#pragma unroll
      for (int r = 0; r < 4; ++r)
        Ob[(size_t)(m * 16 + quad * 4 + r) * 64 + s * 16 + l] = f2bf(o[m][s][r]);
}

// ---------------------------------------------------------------------------
// Kernel 3 (r22): fused combine + output-GEMM + LayerNorm, BARRIER-FREE
// GEMM phase.  The old version's 8 k-steps each ended in __syncthreads()
// whose vmcnt(0)-drain serialized the 64KB sB staging at 1 block/CU (the
// §5 barrier-drain stall, un-hidable).  WOb is 0.5MB = L2/L3-resident, so
// each wave now reads its B-fragments DIRECTLY from global — exact same
// bytes, same MFMA order -> bit-identical output.  Deletes sB (LDS 144 ->
// ~19KB), deletes all 8 k-loop barriers; 16 waves of TLP hide L2 latency
// (m114).  pls/plq no longer overlay sA -> no new hazards; the two LN
// barriers remain.  grid 256 x 1024 thr, block owns 16 token rows.
// ---------------------------------------------------------------------------
__global__ __launch_bounds__(1024) void outfuse_kernel(
    const u16* __restrict__ Opart, const float* __restrict__ Lpart,
    const u16* __restrict__ WOb, const float* __restrict__ bO,
    const float* __restrict__ resid, const float* __restrict__ gamma,
    const float* __restrict__ beta, float* __restrict__ Y)
{
  __shared__ __align__(128) bf16x8 sA[64 * 16];   // [col8][n]  16 KB
  __shared__ float pls[16 * 16];                  // [row][wave]
  __shared__ float plq[16 * 16];
  __shared__ float mrow[16 * 2];                  // mu, inv-sigma

  const int tid = threadIdx.x;
  const int w = tid >> 6, lane = tid & 63, quad = lane >> 4, l = lane & 15;
  const int n0 = blockIdx.x * 16;

  // ---- phase 1: combine -> sA (ctx tile [16 rows][512 cols] as [col8][n])
  {
    const int h = tid >> 7;
    const int n = (tid >> 3) & 15;
    const int vd0 = (tid & 7) * 8;
    float a8[8] = {0, 0, 0, 0, 0, 0, 0, 0};
    float lsum = 0.f;
#pragma unroll
    for (int s = 0; s < 4; ++s) {
      U128 u;
      u.u = *(const uint4*)(Opart + ((size_t)(s * NHEADS + h) * N_TOK + n0 + n) * 64 + vd0);
#pragma unroll
      for (int j = 0; j < 8; ++j) a8[j] += bf2f(u.s[j]);
      lsum += Lpart[((size_t)s * NHEADS + h) * N_TOK + n0 + n];
    }
    float inv = 1.f / lsum;
    U128 o;
#pragma unroll
    for (int j = 0; j < 8; ++j) o.s[j] = f2bf(a8[j] * inv);
    const int col8 = h * 8 + (tid & 7);
    *(uint4*)&sA[col8 * 16 + n] = o.u;
  }
  __syncthreads();

  // ---- phase 2: GEMM out[16][512] = ctx . WOb^T, wave w -> j in [w*32, w*32+32)
  //      B-fragments read directly from global (L2-resident WOb); no barriers.
  const f32x4 zero = {0.f, 0.f, 0.f, 0.f};
  f32x4 acc[2];
  acc[0] = zero; acc[1] = zero;

  for (int kt = 0; kt < 8; ++kt) {
#pragma unroll
    for (int c = 0; c < 2; ++c) {
      bf16x8 af = sA[(kt * 8 + c * 4 + quad) * 16 + l];
#pragma unroll
      for (int s = 0; s < 2; ++s) {
        const int j = w * 32 + s * 16 + l;
        U128 bu;
        bu.u = *(const uint4*)(WOb + (size_t)j * DMODEL + kt * 64 + (c * 4 + quad) * 8);
        acc[s] = __builtin_amdgcn_mfma_f32_16x16x32_bf16(af, bu.b, acc[s], 0, 0, 0);
      }
    }
  }

  // ---- phase 3: bias + residual, LN, write
  float vb[2][4];
#pragma unroll
  for (int s = 0; s < 2; ++s) {
    const int j = w * 32 + s * 16 + l;
    const float bv = bO[j];
#pragma unroll
    for (int r = 0; r < 4; ++r)
      vb[s][r] = acc[s][r] + bv + resid[(size_t)(n0 + quad * 4 + r) * DMODEL + j];
  }
#pragma unroll
  for (int r = 0; r < 4; ++r) {
    float sm = vb[0][r] + vb[1][r];
    float sq = vb[0][r] * vb[0][r] + vb[1][r] * vb[1][r];
#pragma unroll
    for (int mk = 1; mk < 16; mk <<= 1) {
      sm += __shfl_xor(sm, mk);
      sq += __shfl_xor(sq, mk);
    }
    if (l == 0) {
      pls[(quad * 4 + r) * 16 + w] = sm;
      plq[(quad * 4 + r) * 16 + w] = sq;
    }
  }
  __syncthreads();
  if (tid < 16) {
    float sm = 0.f, sq = 0.f;
#pragma unroll
    for (int w2 = 0; w2 < 16; ++w2) { sm += pls[tid * 16 + w2]; sq += plq[tid * 16 + w2]; }
    const float mu = sm * (1.f / DMODEL);
    const float var = sq * (1.f / DMODEL) - mu * mu;
    mrow[tid * 2]     = mu;
    mrow[tid * 2 + 1] = rsqrtf(var + 1e-5f);
  }
  __syncthreads();
#pragma unroll
  for (int s = 0; s < 2; ++s) {
    const int j = w * 32 + s * 16 + l;
    const float gj = gamma[j], bj = beta[j];
#pragma unroll
    for (int r = 0; r < 4; ++r) {
      const int row = quad * 4 + r;
      const float mu = mrow[row * 2], sc = mrow[row * 2 + 1];
      Y[(size_t)(n0 + row) * DMODEL + j] = (vb[s][r] - mu) * sc * gj + bj;
    }
  }
}

// ---------------------------------------------------------------------------
extern "C" void kernel_launch(void* const* d_in, const int* in_sizes, int n_in,
                              void* d_out, int out_size, void* d_ws, size_t ws_size,
                              hipStream_t stream)
{
  const float* Q     = (const float*)d_in[0];
  const float* K     = (const float*)d_in[1];
  const float* V     = (const float*)d_in[2];
  const float* WQ    = (const float*)d_in[3];
  const float* bQ    = (const float*)d_in[4];
  const float* WK    = (const float*)d_in[5];
  const float* bK    = (const float*)d_in[6];
  const float* WV    = (const float*)d_in[7];
  const float* bV    = (const float*)d_in[8];
  const float* WO    = (const float*)d_in[9];
  const float* bO    = (const float*)d_in[10];
  const float* gamma = (const float*)d_in[11];
  const float* beta  = (const float*)d_in[12];

  const size_t MB = 1ull << 20;
  char* ws = (char*)d_ws;
  u16* Qb   = (u16*)(ws + 0 * MB);                  // 4 MB each
  u16* Kb   = (u16*)(ws + 4 * MB);
  u16* Vb   = (u16*)(ws + 8 * MB);
  u16* WQb  = (u16*)(ws + 12 * MB);                 // 0.5 MB each
  u16* WKb  = (u16*)(ws + 12 * MB + 512 * 1024);
  u16* WVb  = (u16*)(ws + 13 * MB);
  u16* WOb  = (u16*)(ws + 13 * MB + 512 * 1024);
  u16* Qs   = (u16*)(ws + 14 * MB);                 // 4 MB each
  u16* Ks   = (u16*)(ws + 18 * MB);
  u16* Vt   = (u16*)(ws + 22 * MB);                 // projected V^T [j][n]
  u16* Opart = (u16*)(ws + 30 * MB);                // 16 MB bf16
  float* Lpart = (float*)(ws + 46 * MB);            // 0.5 MB
  float* out = (float*)d_out;

  cvt7_kernel<<<7168, 256, 0, stream>>>(Q, K, V, WQ, WK, WV, WO,
                                        Qb, Kb, Vb, WQb, WKb, WVb, WOb);
  proj3_kernel<<<dim3(32, 8, 3), 256, 0, stream>>>(Qb, Kb, Vb, WQb, WKb, WVb,
                                                   bQ, bK, bV, Qs, Ks, Vt);
  attn_kernel<<<dim3(32, 16), 512, 0, stream>>>(Qs, Ks, Vt, Opart, Lpart);
  outfuse_kernel<<<256, 1024, 0, stream>>>(Opart, Lpart, WOb, bO, Q,
                                           gamma, beta, out);
}

// Round 13
// 162.724 us; speedup vs baseline: 1.0336x; 1.0336x over previous
//
#include <hip/hip_runtime.h>
#include <cstdint>

#define N_TOK 4096
#define DMODEL 512
#define NHEADS 8
#define HDIM 64

typedef unsigned short u16;
typedef __bf16 bf16x8 __attribute__((ext_vector_type(8)));
typedef float f32x4 __attribute__((ext_vector_type(4)));

union U128 { uint4 u; bf16x8 b; u16 s[8]; };

__device__ __forceinline__ u16 f2bf(float f) {           // RNE
  uint32_t u = __builtin_bit_cast(uint32_t, f);
  u += 0x7FFFu + ((u >> 16) & 1u);
  return (u16)(u >> 16);
}
__device__ __forceinline__ float bf2f(u16 s) {
  uint32_t u = ((uint32_t)s) << 16;
  return __builtin_bit_cast(float, u);
}

#if __has_builtin(__builtin_amdgcn_exp2f)
#define EXP2(x) __builtin_amdgcn_exp2f(x)
#else
#define EXP2(x) __expf((x) * 0.6931471805599453f)
#endif

// v_cvt_pk_bf16_f32: packs two f32 into one u32 of 2 bf16 (RNE), src0 -> lo.
__device__ __forceinline__ uint32_t cvtpk(float lo, float hi) {
  uint32_t r;
  asm("v_cvt_pk_bf16_f32 %0, %1, %2" : "=v"(r) : "v"(lo), "v"(hi));
  return r;
}

// async global->LDS, 16B/lane, dest = wave-uniform base + lane*16
__device__ __forceinline__ void ldg2lds16(const void* g, void* s) {
  __builtin_amdgcn_global_load_lds(
      (const __attribute__((address_space(1))) void*)g,
      (__attribute__((address_space(3))) void*)s, 16, 0, 0);
}

// ---------------------------------------------------------------------------
// Kernel 0: fp32 -> bf16 pre-convert of Q,K,V,WQ,WK,WV,WO.  3584 x 256,
// 8 elems/thread (r23: was 4 — halves block count on a pure-BW kernel;
// f2bf per element unchanged -> bit-identical).
// ---------------------------------------------------------------------------
__global__ __launch_bounds__(256) void cvt7_kernel(
    const float* __restrict__ Q, const float* __restrict__ K, const float* __restrict__ V,
    const float* __restrict__ WQ, const float* __restrict__ WK, const float* __restrict__ WV,
    const float* __restrict__ WO,
    u16* __restrict__ Qb, u16* __restrict__ Kb, u16* __restrict__ Vb,
    u16* __restrict__ WQb, u16* __restrict__ WKb, u16* __restrict__ WVb,
    u16* __restrict__ WOb)
{
  int b = blockIdx.x;
  const float* src; u16* dst; int rel;
  if      (b < 1024) { src = Q;  dst = Qb;  rel = b; }
  else if (b < 2048) { src = K;  dst = Kb;  rel = b - 1024; }
  else if (b < 3072) { src = V;  dst = Vb;  rel = b - 2048; }
  else if (b < 3200) { src = WQ; dst = WQb; rel = b - 3072; }
  else if (b < 3328) { src = WK; dst = WKb; rel = b - 3200; }
  else if (b < 3456) { src = WV; dst = WVb; rel = b - 3328; }
  else               { src = WO; dst = WOb; rel = b - 3456; }
  int i = (rel * 256 + threadIdx.x) * 8;
  float4 f0 = *(const float4*)(src + i);
  float4 f1 = *(const float4*)(src + i + 4);
  ushort4 o0, o1;
  o0.x = f2bf(f0.x); o0.y = f2bf(f0.y); o0.z = f2bf(f0.z); o0.w = f2bf(f0.w);
  o1.x = f2bf(f1.x); o1.y = f2bf(f1.y); o1.z = f2bf(f1.z); o1.w = f2bf(f1.w);
  *(ushort4*)(dst + i) = o0;
  *(ushort4*)(dst + i + 4) = o1;
}

// ---------------------------------------------------------------------------
// Kernel 1 (r20, verified): fused QKV projection with COALESCED staging
// (8 consecutive rows x 128B per global_load_lds, rule-21c swizzle).
// 128x64 tile, m=2, double-buffered.  grid (32, 8, 3), block 256.
// ---------------------------------------------------------------------------
__global__ __launch_bounds__(256) void proj3_kernel(
    const u16* __restrict__ Qb, const u16* __restrict__ Kb, const u16* __restrict__ Vb,
    const u16* __restrict__ WQb, const u16* __restrict__ WKb, const u16* __restrict__ WVb,
    const float* __restrict__ bQ, const float* __restrict__ bK, const float* __restrict__ bV,
    u16* __restrict__ Qs, u16* __restrict__ Ks, u16* __restrict__ Vt)
{
  const int z = blockIdx.z;
  const u16* A      = (z == 0) ? Qb : (z == 1) ? Kb : Vb;
  const u16* W      = (z == 0) ? WQb : (z == 1) ? WKb : WVb;
  const float* bias = (z == 0) ? bQ : (z == 1) ? bK : bV;

  const int m0 = blockIdx.x * 128;
  const int j0 = blockIdx.y * 64;
  const int tid = threadIdx.x;
  const int w = tid >> 6, lane = tid & 63, quad = lane >> 4, l = lane & 15;

  __shared__ bf16x8 sA[2][128 * 8];  // [row][slot] 32 KB
  __shared__ bf16x8 sB[2][64 * 8];   // [row][slot] 16 KB

  const f32x4 zero = {0.f, 0.f, 0.f, 0.f};
  f32x4 acc[2][4];
#pragma unroll
  for (int m = 0; m < 2; ++m)
#pragma unroll
    for (int s = 0; s < 4; ++s) acc[m][s] = zero;

  const int rsub = lane >> 3;            // 0..7: row within 8-row group
  const int gchunk = (lane & 7) ^ rsub;  // pre-swizzled source k-chunk

  auto stage = [&](int kt, int buf) {
    const int k0 = kt * 64;
#pragma unroll
    for (int t = 0; t < 4; ++t) {
      const int row = w * 32 + t * 8;
      const u16* ag = A + (size_t)(m0 + row + rsub) * DMODEL + k0 + gchunk * 8;
      ldg2lds16(ag, (char*)&sA[buf][row * 8]);
    }
#pragma unroll
    for (int i = 0; i < 2; ++i) {
      const int row = w * 16 + i * 8;
      const u16* bg = W + (size_t)(j0 + row + rsub) * DMODEL + k0 + gchunk * 8;
      ldg2lds16(bg, (char*)&sB[buf][row * 8]);
    }
  };

  stage(0, 0);
  __syncthreads();
  for (int kt = 0; kt < 8; ++kt) {
    const int buf = kt & 1;
    if (kt + 1 < 8) stage(kt + 1, buf ^ 1);
#pragma unroll
    for (int c = 0; c < 2; ++c) {
      const int sl = (c * 4 + quad) ^ (l & 7);   // swizzled read slot
      bf16x8 af0 = sA[buf][(w * 32 + l) * 8 + sl];
      bf16x8 af1 = sA[buf][(w * 32 + 16 + l) * 8 + sl];
#pragma unroll
      for (int s = 0; s < 4; ++s) {
        bf16x8 bfb = sB[buf][(s * 16 + l) * 8 + sl];
        acc[0][s] = __builtin_amdgcn_mfma_f32_16x16x32_bf16(af0, bfb, acc[0][s], 0, 0, 0);
        acc[1][s] = __builtin_amdgcn_mfma_f32_16x16x32_bf16(af1, bfb, acc[1][s], 0, 0, 0);
      }
    }
    __syncthreads();
  }

#pragma unroll
  for (int m = 0; m < 2; ++m)
#pragma unroll
    for (int s = 0; s < 4; ++s) {
      int j = j0 + s * 16 + l;
      float bv = bias[j];
      int n0 = m0 + w * 32 + m * 16 + quad * 4;
      if (z < 2) {
        u16* Y = (z == 0) ? Qs : Ks;
#pragma unroll
        for (int r = 0; r < 4; ++r)
          Y[(size_t)(n0 + r) * DMODEL + j] = f2bf(acc[m][s][r] + bv);
      } else {
        ushort4 pk;
        pk.x = f2bf(acc[m][s][0] + bv); pk.y = f2bf(acc[m][s][1] + bv);
        pk.z = f2bf(acc[m][s][2] + bv); pk.w = f2bf(acc[m][s][3] + bv);
        *(ushort4*)(Vt + (size_t)j * N_TOK + n0) = pk;   // V^T write
      }
    }
}

// ---------------------------------------------------------------------------
// Kernel 2: flash attention — r16 VERIFIED version (absmax 0.03125, ~44us,
// conflicts 2.1M): r8 geometry + r14 VALU diet + pbuf XOR-swizzle.  FROZEN.
// (r21 coalesced-staging variant rejected: zero speed change, absmax drift.)
// ---------------------------------------------------------------------------
__global__ __launch_bounds__(512, 4) void attn_kernel(
    const u16* __restrict__ Qs, const u16* __restrict__ Ks,
    const u16* __restrict__ Vt, u16* __restrict__ Opart, float* __restrict__ Lpart)
{
  const int hs = blockIdx.x;                 // h + 8*split
  const int h = hs & 7, split = hs >> 3;
  const int qt = blockIdx.y;
  const int tid = threadIdx.x;
  const int w = tid >> 6, lane = tid & 63, quad = lane >> 4, l = lane & 15;

  __shared__ bf16x8 kch[2][8][64];                 // 16 KB  [buf][d-chunk][key]
  __shared__ bf16x8 vch[2][8][64];                 // 16 KB  [buf][key-chunk][vd]
  __shared__ __align__(128) u16 pbuf[8][32][64];   // 32 KB  [wave][q][128B swizzled row]

  const int wq0 = qt * 256 + w * 32;

  // Q fragments (B-operand), pre-scaled by log2(e)/8
  bf16x8 qf[2][2];
#pragma unroll
  for (int c = 0; c < 2; ++c)
#pragma unroll
    for (int m = 0; m < 2; ++m) {
      U128 u;
      u.u = *(const uint4*)(Qs + (size_t)(wq0 + m * 16 + l) * DMODEL + h * HDIM + c * 32 + quad * 8);
#pragma unroll
      for (int j = 0; j < 8; ++j) u.s[j] = f2bf(bf2f(u.s[j]) * 0.18033688f);
      qf[c][m] = u.b;
    }

  // all-ones B-fragment for the lsum MFMA (bf16 1.0 = 0x3F80)
  U128 onesu;
#pragma unroll
  for (int j = 0; j < 8; ++j) onesu.s[j] = 0x3F80;

  const f32x4 zero = {0.f, 0.f, 0.f, 0.f};
  f32x4 o[2][4];
  f32x4 ol[2];               // lsum accumulators: ol[m][r] = lsum[q=m*16+quad*4+r]
  ol[0] = zero; ol[1] = zero;
#pragma unroll
  for (int m = 0; m < 2; ++m)
#pragma unroll
    for (int s = 0; s < 4; ++s) o[m][s] = zero;

  auto stage = [&](int it, int buf) {
    const int j0 = split * 1024 + it * 64;
    if (w < 4) {            // waves 0-3 stage K (8 KB)
      const u16* kg = Ks + (size_t)(j0 + lane) * DMODEL + h * HDIM + w * 16;
      ldg2lds16(kg,     (char*)&kch[buf][2 * w][0]);
      ldg2lds16(kg + 8, (char*)&kch[buf][2 * w + 1][0]);
    } else {                // waves 4-7 stage V^T (8 KB)
      const int w2 = w - 4;
      const u16* vg = Vt + (size_t)(h * HDIM + lane) * N_TOK + j0 + w2 * 16;
      ldg2lds16(vg,     (char*)&vch[buf][2 * w2][0]);
      ldg2lds16(vg + 8, (char*)&vch[buf][2 * w2 + 1][0]);
    }
  };

  stage(0, 0);
  __syncthreads();

  const unsigned swz = (unsigned)((l & 7) << 4);   // pbuf per-row XOR (row&7 == l&7)

  for (int it = 0; it < 16; ++it) {
    const int buf = it & 1;
    if (it + 1 < 16) stage(it + 1, buf ^ 1);   // prefetch overlaps compute

#pragma unroll
    for (int kh = 0; kh < 2; ++kh) {           // two 32-key halves
#pragma unroll
      for (int tt = 0; tt < 2; ++tt) {
        const int t = kh * 2 + tt;
        f32x4 sacc[2];
        sacc[0] = zero; sacc[1] = zero;
#pragma unroll
        for (int c = 0; c < 2; ++c) {
          bf16x8 kf = kch[buf][c * 4 + quad][t * 16 + l];
          sacc[0] = __builtin_amdgcn_mfma_f32_16x16x32_bf16(kf, qf[c][0], sacc[0], 0, 0, 0);
          sacc[1] = __builtin_amdgcn_mfma_f32_16x16x32_bf16(kf, qf[c][1], sacc[1], 0, 0, 0);
        }
#pragma unroll
        for (int m = 0; m < 2; ++m) {
          uint2 st;
          st.x = cvtpk(EXP2(sacc[m][0]), EXP2(sacc[m][1]));
          st.y = cvtpk(EXP2(sacc[m][2]), EXP2(sacc[m][3]));
          char* pb = (char*)&pbuf[w][m * 16 + l][0];
          *(uint2*)(pb + (((unsigned)(tt * 32 + quad * 8)) ^ swz)) = st;
        }
      }
      // PV for this key half (contraction = 32 keys, quad covers them)
      U128 pf0, pf1;
      const unsigned ro = ((unsigned)(quad * 16)) ^ swz;
      pf0.u = *(const uint4*)((const char*)&pbuf[w][l][0] + ro);
      pf1.u = *(const uint4*)((const char*)&pbuf[w][16 + l][0] + ro);
#pragma unroll
      for (int s = 0; s < 4; ++s) {
        bf16x8 vf = vch[buf][kh * 4 + quad][s * 16 + l];
        o[0][s] = __builtin_amdgcn_mfma_f32_16x16x32_bf16(pf0.b, vf, o[0][s], 0, 0, 0);
        o[1][s] = __builtin_amdgcn_mfma_f32_16x16x32_bf16(pf1.b, vf, o[1][s], 0, 0, 0);
      }
      // lsum = P . 1 on the matrix pipe
      ol[0] = __builtin_amdgcn_mfma_f32_16x16x32_bf16(pf0.b, onesu.b, ol[0], 0, 0, 0);
      ol[1] = __builtin_amdgcn_mfma_f32_16x16x32_bf16(pf1.b, onesu.b, ol[1], 0, 0, 0);
    }
    __syncthreads();   // publishes next buf's loads; orders buf reuse
  }

  // ol[m][r] holds lsum for q = m*16+quad*4+r, replicated across l=0..15.
  if (l == 0) {
    float* Lp = Lpart + ((size_t)split * NHEADS + h) * N_TOK + wq0;
#pragma unroll
    for (int m = 0; m < 2; ++m)
#pragma unroll
      for (int r = 0; r < 4; ++r)
        Lp[m * 16 + quad * 4 + r] = ol[m][r];
  }
  // Opart[split][h][q][vd] bf16 (unnormalized)
  u16* Ob = Opart + ((size_t)(split * NHEADS + h) * N_TOK + wq0) * 64;
#pragma unroll
  for (int m = 0; m < 2; ++m)
#pragma unroll
    for (int s = 0; s < 4; ++s)
#pragma unroll
      for (int r = 0; r < 4; ++r)
        Ob[(size_t)(m * 16 + quad * 4 + r) * 64 + s * 16 + l] = f2bf(o[m][s][r]);
}

// ---------------------------------------------------------------------------
// Kernel 3: fused combine + output-GEMM + LayerNorm (r18 VERIFIED version
// RESTORED — r22's barrier-free direct-global B reads regressed ~3us:
// scattered L2 reads cost more than the 8 barrier drains they removed).
// grid 256 x 1024 thr (16 waves), block owns 16 token rows.
// ---------------------------------------------------------------------------
__global__ __launch_bounds__(1024) void outfuse_kernel(
    const u16* __restrict__ Opart, const float* __restrict__ Lpart,
    const u16* __restrict__ WOb, const float* __restrict__ bO,
    const float* __restrict__ resid, const float* __restrict__ gamma,
    const float* __restrict__ beta, float* __restrict__ Y)
{
  __shared__ __align__(128) char smem[16384 + 2 * 65536];   // 144 KB
  bf16x8* sA = (bf16x8*)smem;                 // [64 col8][16 n]   (16 KB)
  bf16x8* sB = (bf16x8*)(smem + 16384);       // [2][512 j][8 ch'] (2x64 KB)
  float* pls = (float*)smem;                  // reused after GEMM: [16 row][16 wave]
  float* plq = (float*)smem + 256;
  float* mrow = (float*)smem + 512;           // [16][2] mu, inv-sigma

  const int tid = threadIdx.x;
  const int w = tid >> 6, lane = tid & 63, quad = lane >> 4, l = lane & 15;
  const int n0 = blockIdx.x * 16;

  auto stageB = [&](int kt, int buf) {
#pragma unroll
    for (int t = 0; t < 4; ++t) {
      const int jb = w * 32 + t * 8;
      const u16* g = WOb + (size_t)(jb + (lane >> 3)) * DMODEL + kt * 64
                   + (((lane & 7) ^ (lane >> 3)) * 8);
      ldg2lds16(g, (char*)&sB[(size_t)buf * 4096 + jb * 8]);
    }
  };

  stageB(0, 0);

  // ---- phase 1: combine -> sA (ctx tile [16 rows][512 cols] as [col8][n])
  {
    const int h = tid >> 7;
    const int n = (tid >> 3) & 15;
    const int vd0 = (tid & 7) * 8;
    float a8[8] = {0, 0, 0, 0, 0, 0, 0, 0};
    float lsum = 0.f;
#pragma unroll
    for (int s = 0; s < 4; ++s) {
      U128 u;
      u.u = *(const uint4*)(Opart + ((size_t)(s * NHEADS + h) * N_TOK + n0 + n) * 64 + vd0);
#pragma unroll
      for (int j = 0; j < 8; ++j) a8[j] += bf2f(u.s[j]);
      lsum += Lpart[((size_t)s * NHEADS + h) * N_TOK + n0 + n];
    }
    float inv = 1.f / lsum;
    U128 o;
#pragma unroll
    for (int j = 0; j < 8; ++j) o.s[j] = f2bf(a8[j] * inv);
    const int col8 = h * 8 + (tid & 7);
    *(uint4*)&sA[col8 * 16 + n] = o.u;
  }
  __syncthreads();

  // ---- phase 2: GEMM out[16][512] = ctx . WOb^T, wave w -> j in [w*32, w*32+32)
  const f32x4 zero = {0.f, 0.f, 0.f, 0.f};
  f32x4 acc[2];
  acc[0] = zero; acc[1] = zero;

  for (int kt = 0; kt < 8; ++kt) {
    const int buf = kt & 1;
    if (kt + 1 < 8) stageB(kt + 1, buf ^ 1);
#pragma unroll
    for (int c = 0; c < 2; ++c) {
      bf16x8 af = sA[(kt * 8 + c * 4 + quad) * 16 + l];
#pragma unroll
      for (int s = 0; s < 2; ++s) {
        const int j = w * 32 + s * 16 + l;
        bf16x8 bfb = sB[(size_t)buf * 4096 + j * 8 + ((c * 4 + quad) ^ (l & 7))];
        acc[s] = __builtin_amdgcn_mfma_f32_16x16x32_bf16(af, bfb, acc[s], 0, 0, 0);
      }
    }
    __syncthreads();
  }

  // ---- phase 3: bias + residual, LN, write
  float vb[2][4];
#pragma unroll
  for (int s = 0; s < 2; ++s) {
    const int j = w * 32 + s * 16 + l;
    const float bv = bO[j];
#pragma unroll
    for (int r = 0; r < 4; ++r)
      vb[s][r] = acc[s][r] + bv + resid[(size_t)(n0 + quad * 4 + r) * DMODEL + j];
  }
#pragma unroll
  for (int r = 0; r < 4; ++r) {
    float sm = vb[0][r] + vb[1][r];
    float sq = vb[0][r] * vb[0][r] + vb[1][r] * vb[1][r];
#pragma unroll
    for (int mk = 1; mk < 16; mk <<= 1) {
      sm += __shfl_xor(sm, mk);
      sq += __shfl_xor(sq, mk);
    }
    if (l == 0) {
      pls[(quad * 4 + r) * 16 + w] = sm;
      plq[(quad * 4 + r) * 16 + w] = sq;
    }
  }
  __syncthreads();
  if (tid < 16) {
    float sm = 0.f, sq = 0.f;
#pragma unroll
    for (int w2 = 0; w2 < 16; ++w2) { sm += pls[tid * 16 + w2]; sq += plq[tid * 16 + w2]; }
    const float mu = sm * (1.f / DMODEL);
    const float var = sq * (1.f / DMODEL) - mu * mu;
    mrow[tid * 2]     = mu;
    mrow[tid * 2 + 1] = rsqrtf(var + 1e-5f);
  }
  __syncthreads();
#pragma unroll
  for (int s = 0; s < 2; ++s) {
    const int j = w * 32 + s * 16 + l;
    const float gj = gamma[j], bj = beta[j];
#pragma unroll
    for (int r = 0; r < 4; ++r) {
      const int row = quad * 4 + r;
      const float mu = mrow[row * 2], sc = mrow[row * 2 + 1];
      Y[(size_t)(n0 + row) * DMODEL + j] = (vb[s][r] - mu) * sc * gj + bj;
    }
  }
}

// ---------------------------------------------------------------------------
extern "C" void kernel_launch(void* const* d_in, const int* in_sizes, int n_in,
                              void* d_out, int out_size, void* d_ws, size_t ws_size,
                              hipStream_t stream)
{
  const float* Q     = (const float*)d_in[0];
  const float* K     = (const float*)d_in[1];
  const float* V     = (const float*)d_in[2];
  const float* WQ    = (const float*)d_in[3];
  const float* bQ    = (const float*)d_in[4];
  const float* WK    = (const float*)d_in[5];
  const float* bK    = (const float*)d_in[6];
  const float* WV    = (const float*)d_in[7];
  const float* bV    = (const float*)d_in[8];
  const float* WO    = (const float*)d_in[9];
  const float* bO    = (const float*)d_in[10];
  const float* gamma = (const float*)d_in[11];
  const float* beta  = (const float*)d_in[12];

  const size_t MB = 1ull << 20;
  char* ws = (char*)d_ws;
  u16* Qb   = (u16*)(ws + 0 * MB);                  // 4 MB each
  u16* Kb   = (u16*)(ws + 4 * MB);
  u16* Vb   = (u16*)(ws + 8 * MB);
  u16* WQb  = (u16*)(ws + 12 * MB);                 // 0.5 MB each
  u16* WKb  = (u16*)(ws + 12 * MB + 512 * 1024);
  u16* WVb  = (u16*)(ws + 13 * MB);
  u16* WOb  = (u16*)(ws + 13 * MB + 512 * 1024);
  u16* Qs   = (u16*)(ws + 14 * MB);                 // 4 MB each
  u16* Ks   = (u16*)(ws + 18 * MB);
  u16* Vt   = (u16*)(ws + 22 * MB);                 // projected V^T [j][n]
  u16* Opart = (u16*)(ws + 30 * MB);                // 16 MB bf16
  float* Lpart = (float*)(ws + 46 * MB);            // 0.5 MB
  float* out = (float*)d_out;

  cvt7_kernel<<<3584, 256, 0, stream>>>(Q, K, V, WQ, WK, WV, WO,
                                        Qb, Kb, Vb, WQb, WKb, WVb, WOb);
  proj3_kernel<<<dim3(32, 8, 3), 256, 0, stream>>>(Qb, Kb, Vb, WQb, WKb, WVb,
                                                   bQ, bK, bV, Qs, Ks, Vt);
  attn_kernel<<<dim3(32, 16), 512, 0, stream>>>(Qs, Ks, Vt, Opart, Lpart);
  outfuse_kernel<<<256, 1024, 0, stream>>>(Opart, Lpart, WOb, bO, Q,
                                           gamma, beta, out);
}